// Round 7
// baseline (124.454 us; speedup 1.0000x reference)
//
#include <hip/hip_runtime.h>
#include <math.h>

#define NB 128
#define NN 16
#define MM 32
#define DD 128
#define NACT 8
#define HH 64

// -------- scratch layout (floats) --------
#define OFF_G   0                        // Gram Wq@Wk^T           [128][128]
#define OFF_GO  16384                    // Gram Wq_o@Wk_o^T       [128][128]
#define OFF_Q   32768                    // q'  = st@G             [2048][128]
#define OFF_QO  (OFF_Q  + 2048*128)      // qo' = st@Go            [2048][128]
#define OFF_AA  (OFF_QO + 2048*128)      // avact                  [2048][128]
#define OFF_DF  (OFF_AA + 2048*128)      // diff = avpol-avact     [2048][128]
#define OFF_AVO (OFF_DF + 2048*128)      // avo                    [4096][128]
#define OFF_P   (OFF_AVO + 4096*128)     // P  = avact@W1a         [2048][64]
#define OFF_V   (OFF_P  + 2048*64)       // V  = diff@W1a          [2048][64]
#define OFF_PO  (OFF_V  + 2048*64)       // Po = avo@W1b           [4096][64]
#define OFF_S   (OFF_PO + 4096*64)       // scaled scores          [128][16][16]
#define OFF_SO  (OFF_S  + 128*256)       // scaled scores_o        [128][16][32]
#define WS_FLOATS (OFF_SO + 128*512)     // 2,228,224 floats (~8.9 MB)

__device__ float g_ws[WS_FLOATS];

// ---------------- k0: Gram matrices G = Wq @ Wk^T, Go = Wq_o @ Wk_o^T ----------------
__launch_bounds__(256)
__global__ void k0_gram(const float* __restrict__ Wq,  const float* __restrict__ Wk,
                        const float* __restrict__ Wqo, const float* __restrict__ Wko) {
    __shared__ float sA[16 * 129];
    __shared__ float sB[16 * 129];
    const int blk = blockIdx.x;
    const int mat = blk >> 6;
    const int tile = blk & 63;
    const int r0 = (tile >> 3) * 16, c0 = (tile & 7) * 16;
    const float* A  = mat ? Wqo : Wq;
    const float* Bm = mat ? Wko : Wk;
    float* outp = g_ws + (mat ? OFF_GO : OFF_G);
    const int t = threadIdx.x;
    for (int idx = t; idx < 16 * 128; idx += 256) {
        int r = idx >> 7, c = idx & 127;
        sA[r * 129 + c] = A [(r0 + r) * 128 + c];
        sB[r * 129 + c] = Bm[(c0 + r) * 128 + c];
    }
    __syncthreads();
    const int r = t >> 4, c = t & 15;
    float acc = 0.f;
    #pragma unroll 8
    for (int o = 0; o < 128; ++o) acc += sA[r * 129 + o] * sB[c * 129 + o];
    outp[(r0 + r) * 128 + (c0 + c)] = acc;
}

// ---------------- k_proj: flattened GEMM for all first-level projections ----------------
// 32x32 tiles, 256 thr, 2x2/thread. blocks 0..767: self (2048 rows x {q'|qo'|av}),
// blocks 768..1279: other (4096 rows x avo).
__launch_bounds__(256)
__global__ void k_proj(const float* __restrict__ states,   const float* __restrict__ policies,
                       const float* __restrict__ actions,  const float* __restrict__ states_o,
                       const float* __restrict__ actions_o,
                       const float* __restrict__ Wv, const float* __restrict__ Wvo) {
    __shared__ float AT[128][34];     // A tile transposed [K][row]
    __shared__ float s_c1[32][NACT];  // act (self) / act_o (other)
    __shared__ float s_c2[32][NACT];  // pol (self)
    const int t = threadIdx.x;
    const int tx = t & 15, ty = t >> 4;
    const int blk = blockIdx.x;

    const float* Asrc; const float* Bsrc; float* dst;
    int bcol, mode, r0;               // mode 0: plain, 1: self-av (avact+diff), 2: other-av
    if (blk < 768) {
        int rt = blk / 12, ct = blk % 12;
        r0 = rt * 32;
        Asrc = states + r0 * 128;
        if (ct < 4)      { Bsrc = g_ws + OFF_G;  bcol = ct * 32;       dst = g_ws + OFF_Q  + r0 * 128; mode = 0; }
        else if (ct < 8) { Bsrc = g_ws + OFF_GO; bcol = (ct - 4) * 32; dst = g_ws + OFF_QO + r0 * 128; mode = 0; }
        else             { Bsrc = Wv;            bcol = (ct - 8) * 32; dst = g_ws + OFF_AA + r0 * 128; mode = 1; }
    } else {
        int tile = blk - 768;
        int rt = tile >> 2, ct = tile & 3;
        r0 = rt * 32;
        Asrc = states_o + r0 * 128;
        Bsrc = Wvo; bcol = ct * 32; dst = g_ws + OFF_AVO + r0 * 128; mode = 2;
    }

    // stage A (32x128) transposed into LDS
    #pragma unroll
    for (int u = 0; u < 4; ++u) {
        int f4 = t + u * 256;
        int row = f4 >> 5, c4 = (f4 & 31) * 4;
        float4 v = *(const float4*)(Asrc + row * 128 + c4);
        AT[c4 + 0][row] = v.x; AT[c4 + 1][row] = v.y;
        AT[c4 + 2][row] = v.z; AT[c4 + 3][row] = v.w;
    }
    {
        int row = t >> 3, k = t & 7;
        if (mode == 1) {
            s_c1[row][k] = actions [(r0 + row) * NACT + k];
            s_c2[row][k] = policies[(r0 + row) * NACT + k];
        } else if (mode == 2) {
            s_c1[row][k] = actions_o[(r0 + row) * NACT + k];
        }
    }
    __syncthreads();

    const int cc = bcol + 2 * tx;     // column pair (cc, cc+1)
    float a00 = 0.f, a01 = 0.f, a10 = 0.f, a11 = 0.f;
    #pragma unroll 8
    for (int kk = 0; kk < 128; ++kk) {
        float2 a  = *(const float2*)&AT[kk][2 * ty];            // rows 2ty,2ty+1 (broadcast)
        float2 bv = *(const float2*)(Bsrc + kk * 128 + cc);     // L1-resident weight slice
        a00 += a.x * bv.x; a01 += a.x * bv.y;
        a10 += a.y * bv.x; a11 += a.y * bv.y;
    }

    if (mode == 0) {
        *(float2*)(dst + (2 * ty)     * 128 + cc) = make_float2(a00, a01);
        *(float2*)(dst + (2 * ty + 1) * 128 + cc) = make_float2(a10, a11);
    } else if (mode == 1) {
        float aa00 = a00, aa01 = a01, aa10 = a10, aa11 = a11;
        float ap00 = a00, ap01 = a01, ap10 = a10, ap11 = a11;
        #pragma unroll
        for (int k = 0; k < NACT; ++k) {
            float2 w = *(const float2*)(Wv + (128 + k) * 128 + cc);
            float c1a = s_c1[2 * ty][k], c1b = s_c1[2 * ty + 1][k];
            float c2a = s_c2[2 * ty][k], c2b = s_c2[2 * ty + 1][k];
            aa00 += c1a * w.x; aa01 += c1a * w.y; aa10 += c1b * w.x; aa11 += c1b * w.y;
            ap00 += c2a * w.x; ap01 += c2a * w.y; ap10 += c2b * w.x; ap11 += c2b * w.y;
        }
        aa00 = tanhf(aa00); aa01 = tanhf(aa01); aa10 = tanhf(aa10); aa11 = tanhf(aa11);
        ap00 = tanhf(ap00); ap01 = tanhf(ap01); ap10 = tanhf(ap10); ap11 = tanhf(ap11);
        float* ddf = g_ws + OFF_DF + r0 * 128;
        *(float2*)(dst + (2 * ty)     * 128 + cc) = make_float2(aa00, aa01);
        *(float2*)(dst + (2 * ty + 1) * 128 + cc) = make_float2(aa10, aa11);
        *(float2*)(ddf + (2 * ty)     * 128 + cc) = make_float2(ap00 - aa00, ap01 - aa01);
        *(float2*)(ddf + (2 * ty + 1) * 128 + cc) = make_float2(ap10 - aa10, ap11 - aa11);
    } else {
        #pragma unroll
        for (int k = 0; k < NACT; ++k) {
            float2 w = *(const float2*)(Wvo + (128 + k) * 128 + cc);
            float c1a = s_c1[2 * ty][k], c1b = s_c1[2 * ty + 1][k];
            a00 += c1a * w.x; a01 += c1a * w.y; a10 += c1b * w.x; a11 += c1b * w.y;
        }
        *(float2*)(dst + (2 * ty)     * 128 + cc) = make_float2(tanhf(a00), tanhf(a01));
        *(float2*)(dst + (2 * ty + 1) * 128 + cc) = make_float2(tanhf(a10), tanhf(a11));
    }
}

// ---------------- k_w1: P/V/Po GEMM (+ per-batch score tiles) ----------------
// blocks 0..511: 32x32 tiles over rows [avact|diff|avo] (8192) x 64 cols of W1a/W1b.
// blocks 512..639: self score tile per batch. blocks 640..767: other score tile per batch.
__launch_bounds__(256)
__global__ void k_w1(const float* __restrict__ states, const float* __restrict__ states_o,
                     const float* __restrict__ W1) {
    __shared__ float smem[6336];
    const int blk = blockIdx.x, t = threadIdx.x;
    const float scale = 0.08838834764831845f;   // 1/sqrt(128)

    if (blk < 512) {
        const int rt = blk >> 1, ct = blk & 1;
        const int fr = rt * 32;
        const float* Asrc; const float* Bsrc; float* dst;
        if (fr < 2048)      { Asrc = g_ws + OFF_AA  + fr * 128;          Bsrc = W1;            dst = g_ws + OFF_P  + fr * 64; }
        else if (fr < 4096) { Asrc = g_ws + OFF_DF  + (fr - 2048) * 128; Bsrc = W1;            dst = g_ws + OFF_V  + (fr - 2048) * 64; }
        else                { Asrc = g_ws + OFF_AVO + (fr - 4096) * 128; Bsrc = W1 + 128 * 64; dst = g_ws + OFF_PO + (fr - 4096) * 64; }
        #pragma unroll
        for (int u = 0; u < 4; ++u) {
            int f4 = t + u * 256;
            int row = f4 >> 5, c4 = (f4 & 31) * 4;
            float4 v = *(const float4*)(Asrc + row * 128 + c4);
            smem[(c4 + 0) * 34 + row] = v.x; smem[(c4 + 1) * 34 + row] = v.y;
            smem[(c4 + 2) * 34 + row] = v.z; smem[(c4 + 3) * 34 + row] = v.w;
        }
        __syncthreads();
        const int tx = t & 15, ty = t >> 4;
        const int cc = ct * 32 + 2 * tx;
        float a00 = 0.f, a01 = 0.f, a10 = 0.f, a11 = 0.f;
        #pragma unroll 8
        for (int kk = 0; kk < 128; ++kk) {
            float2 a  = *(const float2*)&smem[kk * 34 + 2 * ty];
            float2 bv = *(const float2*)(Bsrc + kk * 64 + cc);
            a00 += a.x * bv.x; a01 += a.x * bv.y;
            a10 += a.y * bv.x; a11 += a.y * bv.y;
        }
        *(float2*)(dst + (2 * ty)     * 64 + cc) = make_float2(a00, a01);
        *(float2*)(dst + (2 * ty + 1) * 64 + cc) = make_float2(a10, a11);
    } else if (blk < 640) {
        const int b = blk - 512;        // score[i,j] = q'[b,i] . st[b,j]
        float* sq  = smem;              // [16][132]
        float* sst = smem + 2112;       // [16][132]
        #pragma unroll
        for (int u = 0; u < 2; ++u) {
            int f4 = t + u * 256;
            int row = f4 >> 5, c4 = (f4 & 31) * 4;
            *(float4*)&sq [row * 132 + c4] = *(const float4*)(g_ws + OFF_Q + (b * 16 + row) * 128 + c4);
            *(float4*)&sst[row * 132 + c4] = *(const float4*)(states      + (b * 16 + row) * 128 + c4);
        }
        __syncthreads();
        const int i = t >> 4, j = t & 15;
        float acc = 0.f;
        #pragma unroll 8
        for (int d = 0; d < 128; ++d) acc += sq[i * 132 + d] * sst[j * 132 + d];
        g_ws[OFF_S + b * 256 + t] = acc * scale;
    } else {
        const int b = blk - 640;        // score_o[i,m] = qo'[b,i] . st_o[b,m]
        float* sq  = smem;              // [16][132]
        float* sso = smem + 2112;       // [32][132]
        #pragma unroll
        for (int u = 0; u < 2; ++u) {
            int f4 = t + u * 256;
            int row = f4 >> 5, c4 = (f4 & 31) * 4;
            *(float4*)&sq[row * 132 + c4] = *(const float4*)(g_ws + OFF_QO + (b * 16 + row) * 128 + c4);
        }
        #pragma unroll
        for (int u = 0; u < 4; ++u) {
            int f4 = t + u * 256;
            int row = f4 >> 5, c4 = (f4 & 31) * 4;
            *(float4*)&sso[row * 132 + c4] = *(const float4*)(states_o + (b * 32 + row) * 128 + c4);
        }
        __syncthreads();
        const int m = t & 31, i0 = t >> 5;   // outputs (i0,m) and (i0+8,m)
        float acc0 = 0.f, acc1 = 0.f;
        #pragma unroll 8
        for (int d = 0; d < 128; ++d) {
            float s = sso[m * 132 + d];
            acc0 += sq[i0 * 132 + d] * s;
            acc1 += sq[(i0 + 8) * 132 + d] * s;
        }
        g_ws[OFF_SO + b * 512 + i0 * 32 + m]       = acc0 * scale;
        g_ws[OFF_SO + b * 512 + (i0 + 8) * 32 + m] = acc1 * scale;
    }
}

// ---------------- k2: softmaxes, U = w@P + wo@Po, value ----------------
__launch_bounds__(256)
__global__ void k2_fin(const float* __restrict__ W2, float* __restrict__ out) {
    __shared__ float s_w [16][17];
    __shared__ float s_wo[16][33];
    __shared__ float s_P [16 * 64];
    __shared__ float s_Po[32 * 64];
    __shared__ float s_V [16][65];
    __shared__ float s_U [16][65];
    __shared__ float s_W2[64];
    const int b = blockIdx.x, t = threadIdx.x;

    s_w[t >> 4][t & 15] = g_ws[OFF_S + b * 256 + t];
    s_wo[t >> 5][t & 31]            = g_ws[OFF_SO + b * 512 + t];
    s_wo[(t + 256) >> 5][t & 31]    = g_ws[OFF_SO + b * 512 + 256 + t];
    ((float4*)s_P)[t] = ((const float4*)(g_ws + OFF_P + b * 1024))[t];
    ((float4*)s_Po)[t]       = ((const float4*)(g_ws + OFF_PO + b * 2048))[t];
    ((float4*)s_Po)[t + 256] = ((const float4*)(g_ws + OFF_PO + b * 2048))[t + 256];
    #pragma unroll
    for (int u = 0; u < 4; ++u) {
        int idx = t + u * 256;
        s_V[idx >> 6][idx & 63] = g_ws[OFF_V + b * 1024 + idx];
    }
    if (t < 64) s_W2[t] = W2[t];
    __syncthreads();

    if (t < 16) {                       // softmax over key axis j
        float mx = -1e30f;
        #pragma unroll
        for (int j = 0; j < NN; ++j) mx = fmaxf(mx, s_w[t][j]);
        float e[NN], sum = 0.f;
        #pragma unroll
        for (int j = 0; j < NN; ++j) { e[j] = expf(s_w[t][j] - mx); sum += e[j]; }
        float inv = 1.f / sum;
        #pragma unroll
        for (int j = 0; j < NN; ++j) s_w[t][j] = e[j] * inv;
    } else if (t >= 64 && t < 96) {     // softmax over agent axis i
        int m = t - 64;
        float mx = -1e30f;
        #pragma unroll
        for (int i = 0; i < NN; ++i) mx = fmaxf(mx, s_wo[i][m]);
        float e[NN], sum = 0.f;
        #pragma unroll
        for (int i = 0; i < NN; ++i) { e[i] = expf(s_wo[i][m] - mx); sum += e[i]; }
        float inv = 1.f / sum;
        #pragma unroll
        for (int i = 0; i < NN; ++i) s_wo[i][m] = e[i] * inv;
    }
    __syncthreads();

    out[NB * 256 + b * 256 + t] = s_w[t >> 4][t & 15];
    out[2 * NB * 256 + b * 512 + t]       = s_wo[t >> 5][t & 31];
    out[2 * NB * 256 + b * 512 + 256 + t] = s_wo[(t + 256) >> 5][t & 31];

    {   // U[i,h0..h0+3]
        int i = t >> 4, h0 = (t & 15) * 4;
        float u0 = 0.f, u1 = 0.f, u2 = 0.f, u3 = 0.f;
        #pragma unroll
        for (int k = 0; k < NN; ++k) {
            float w = s_w[i][k];
            float4 p = *(const float4*)&s_P[k * 64 + h0];
            u0 += w * p.x; u1 += w * p.y; u2 += w * p.z; u3 += w * p.w;
        }
        #pragma unroll
        for (int m = 0; m < MM; ++m) {
            float w = s_wo[i][m];
            float4 p = *(const float4*)&s_Po[m * 64 + h0];
            u0 += w * p.x; u1 += w * p.y; u2 += w * p.z; u3 += w * p.w;
        }
        s_U[i][h0] = u0; s_U[i][h0 + 1] = u1; s_U[i][h0 + 2] = u2; s_U[i][h0 + 3] = u3;
    }
    __syncthreads();

    {   // value[i,j]
        int i = t >> 4, j = t & 15;
        float wij = s_w[i][j];
        float acc = 0.f;
        #pragma unroll
        for (int h = 0; h < HH; ++h) {
            float x = s_U[i][h] + wij * s_V[j][h];
            x = (x > 0.f) ? x : 0.01f * x;
            acc += x * s_W2[h];
        }
        out[b * 256 + t] = acc;
    }
}

extern "C" void kernel_launch(void* const* d_in, const int* in_sizes, int n_in,
                              void* d_out, int out_size, void* d_ws, size_t ws_size,
                              hipStream_t stream) {
    const float* states    = (const float*)d_in[0];
    const float* policies  = (const float*)d_in[1];
    const float* actions   = (const float*)d_in[2];
    const float* states_o  = (const float*)d_in[3];
    const float* actions_o = (const float*)d_in[4];
    const float* Wk        = (const float*)d_in[5];
    const float* Wq        = (const float*)d_in[6];
    const float* Wv        = (const float*)d_in[7];
    const float* Wk_o      = (const float*)d_in[8];
    const float* Wq_o      = (const float*)d_in[9];
    const float* Wv_o      = (const float*)d_in[10];
    const float* W1        = (const float*)d_in[11];
    const float* W2        = (const float*)d_in[12];
    float* out = (float*)d_out;

    hipLaunchKernelGGL(k0_gram, dim3(128),  dim3(256), 0, stream, Wq, Wk, Wq_o, Wk_o);
    hipLaunchKernelGGL(k_proj,  dim3(1280), dim3(256), 0, stream,
                       states, policies, actions, states_o, actions_o, Wv, Wv_o);
    hipLaunchKernelGGL(k_w1,    dim3(768),  dim3(256), 0, stream, states, states_o, W1);
    hipLaunchKernelGGL(k2_fin,  dim3(128),  dim3(256), 0, stream, W2, out);
}

// Round 9
// 118.206 us; speedup vs baseline: 1.0529x; 1.0529x over previous
//
#include <hip/hip_runtime.h>
#include <math.h>

#define NB 128
#define NN 16
#define MM 32
#define DD 128
#define NACT 8
#define HH 64

// ---- static device scratch (floats); fully rewritten by k_sides every call ----
#define WS_W  0                    // weight (softmaxed)  [128][16][16]
#define WS_V  32768                // V  = diff@W1a       [128][16][64]
#define WS_US 163840               // Us = w@ (avact@W1a) [128][16][64]
#define WS_UO 294912               // Uo = wo@(avo@W1b)   [128][16][64]
#define WS_FLOATS (WS_UO + 131072) // 425,984 floats (~1.7 MB)

__device__ float g_ws[WS_FLOATS];

// ---- LDS layout (floats), one buffer, per-side views ----
// side A: st[16][132] q[16][132] k[16][132] aa[16][132] df[16][132] P[16][68] w[16][17] act[128] pol[128]
#define A_ST 0
#define A_Q  2112
#define A_K  4224
#define A_AA 6336
#define A_DF 8448
#define A_P  10560
#define A_W  11648
#define A_AC 11920
#define A_PO 12048
// side B: st[16][132] sto[32][132] qo[16][132] koT[128][33] avo[32][132] Po[32][68] wo[16][33] acto[256]
#define B_ST  0
#define B_STO 2112
#define B_QO  6336
#define B_KOT 8448
#define B_AVO 12672
#define B_PO  16896
#define B_WO  19072
#define B_AO  19600
#define SM_FLOATS 19856

__device__ __forceinline__ float4 tanh4(float4 v) {
    float4 r; r.x = tanhf(v.x); r.y = tanhf(v.y); r.z = tanhf(v.z); r.w = tanhf(v.w); return r;
}
__device__ __forceinline__ void fma4(float4& a, float s, const float4& w) {
    a.x += s * w.x; a.y += s * w.y; a.z += s * w.z; a.w += s * w.w;
}

// grid 256: blockIdx = 2*b + side. side 0: self attention branch. side 1: other branch.
__launch_bounds__(512, 1)
__global__ void k_sides(const float* __restrict__ states,   const float* __restrict__ policies,
                        const float* __restrict__ actions,  const float* __restrict__ states_o,
                        const float* __restrict__ actions_o,
                        const float* __restrict__ Wq,  const float* __restrict__ Wk,
                        const float* __restrict__ Wv,  const float* __restrict__ Wqo,
                        const float* __restrict__ Wko, const float* __restrict__ Wvo,
                        const float* __restrict__ W1,
                        float* __restrict__ out) {
    __shared__ float sm[SM_FLOATS];
    const int b = blockIdx.x >> 1;
    const int side = blockIdx.x & 1;
    const int t = threadIdx.x;
    const float scale = 0.08838834764831845f;   // 1/sqrt(128)

    if (side == 0) {
        // ---------- P0: load st, act, pol ----------
        {
            int row = t >> 5, c4 = (t & 31) * 4;
            *(float4*)&sm[A_ST + row * 132 + c4] = *(const float4*)(states + b * 2048 + row * 128 + c4);
            if (t < 128) sm[A_AC + t] = actions [b * 128 + t];
            else if (t < 256) sm[A_PO + (t - 128)] = policies[b * 128 + (t - 128)];
        }
        __syncthreads();
        // ---------- P1: q,k = st@{Wq,Wk}; avact/avpol = tanh(st@Wv + tail) ----------
        {
            const int i = t >> 5, c4 = (t & 31) * 4;
            float4 aq = {0,0,0,0}, ak = {0,0,0,0}, av = {0,0,0,0};
            #pragma unroll 4
            for (int kk = 0; kk < DD; ++kk) {
                float x = sm[A_ST + i * 132 + kk];
                fma4(aq, x, *(const float4*)(Wq + kk * 128 + c4));
                fma4(ak, x, *(const float4*)(Wk + kk * 128 + c4));
                fma4(av, x, *(const float4*)(Wv + kk * 128 + c4));
            }
            float4 aa = av, ap = av;
            #pragma unroll
            for (int kk = 0; kk < NACT; ++kk) {
                float4 wv = *(const float4*)(Wv + (DD + kk) * 128 + c4);
                fma4(aa, sm[A_AC + i * NACT + kk], wv);
                fma4(ap, sm[A_PO + i * NACT + kk], wv);
            }
            aa = tanh4(aa); ap = tanh4(ap);
            float4 df; df.x = ap.x - aa.x; df.y = ap.y - aa.y; df.z = ap.z - aa.z; df.w = ap.w - aa.w;
            *(float4*)&sm[A_Q  + i * 132 + c4] = aq;
            *(float4*)&sm[A_K  + i * 132 + c4] = ak;
            *(float4*)&sm[A_AA + i * 132 + c4] = aa;
            *(float4*)&sm[A_DF + i * 132 + c4] = df;
        }
        __syncthreads();
        // ---------- P2: scores (t<256) || P = avact@W1a, V = diff@W1a (t>=256) ----------
        if (t < 256) {
            int i = t >> 4, j = t & 15;
            float acc = 0.f;
            #pragma unroll 8
            for (int d = 0; d < DD; ++d) acc += sm[A_Q + i * 132 + d] * sm[A_K + j * 132 + d];
            sm[A_W + i * 17 + j] = acc * scale;
        } else {
            int tt = t - 256, i = tt >> 4, h4 = (tt & 15) * 4;
            float4 accp = {0,0,0,0}, accv = {0,0,0,0};
            #pragma unroll 4
            for (int kk = 0; kk < DD; ++kk) {
                float4 w4 = *(const float4*)(W1 + kk * HH + h4);
                fma4(accp, sm[A_AA + i * 132 + kk], w4);
                fma4(accv, sm[A_DF + i * 132 + kk], w4);
            }
            *(float4*)&sm[A_P + i * 68 + h4] = accp;
            *(float4*)(g_ws + WS_V + b * 1024 + i * 64 + h4) = accv;
        }
        __syncthreads();
        // ---------- P3: softmax over key axis j ----------
        if (t < NN) {
            float mx = -1e30f;
            #pragma unroll
            for (int j = 0; j < NN; ++j) mx = fmaxf(mx, sm[A_W + t * 17 + j]);
            float e[NN], sum = 0.f;
            #pragma unroll
            for (int j = 0; j < NN; ++j) { e[j] = expf(sm[A_W + t * 17 + j] - mx); sum += e[j]; }
            float inv = 1.f / sum;
            #pragma unroll
            for (int j = 0; j < NN; ++j) sm[A_W + t * 17 + j] = e[j] * inv;
        }
        __syncthreads();
        // ---------- P4: write weight; Us = w @ P ----------
        if (t < 256) {
            float wv = sm[A_W + (t >> 4) * 17 + (t & 15)];
            out[NB * 256 + b * 256 + t] = wv;
            g_ws[WS_W + b * 256 + t] = wv;
        }
        {
            int i = t >> 5, h2 = (t & 31) * 2;
            float u0 = 0.f, u1 = 0.f;
            #pragma unroll
            for (int k = 0; k < NN; ++k) {
                float wv = sm[A_W + i * 17 + k];
                u0 += wv * sm[A_P + k * 68 + h2];
                u1 += wv * sm[A_P + k * 68 + h2 + 1];
            }
            *(float2*)(g_ws + WS_US + b * 1024 + i * 64 + h2) = make_float2(u0, u1);
        }
    } else {
        // ---------- P0: load st, st_o, act_o ----------
        {
            int row = t >> 5, c4 = (t & 31) * 4;
            *(float4*)&sm[B_ST + row * 132 + c4] = *(const float4*)(states + b * 2048 + row * 128 + c4);
            int i2 = t + 512, row2 = (i2 >> 5) - 16, c42 = (i2 & 31) * 4;
            *(float4*)&sm[B_STO + row2 * 132 + c42] = *(const float4*)(states_o + b * 4096 + row2 * 128 + c42);
            int i3 = t + 1024, row3 = (i3 >> 5) - 32, c43 = (i3 & 31) * 4;
            *(float4*)&sm[B_STO + (row3 + 16) * 132 + c43] = *(const float4*)(states_o + b * 4096 + (row3 + 16) * 128 + c43);
            if (t < 256) sm[B_AO + t] = actions_o[b * 256 + t];
        }
        __syncthreads();
        // ---------- P1: qo = st@Wqo ; ko = st_o@Wko (store koT) ; avo = tanh(st_o@Wvo + tail) ----------
        {
            const int r = t >> 5, c4 = (t & 31) * 4;
            float4 aqo = {0,0,0,0}, ak0 = {0,0,0,0}, ak1 = {0,0,0,0}, av0 = {0,0,0,0}, av1 = {0,0,0,0};
            #pragma unroll 2
            for (int kk = 0; kk < DD; ++kk) {
                float xs = sm[B_ST  + r * 132 + kk];
                float x0 = sm[B_STO + r * 132 + kk];
                float x1 = sm[B_STO + (r + 16) * 132 + kk];
                float4 wq4 = *(const float4*)(Wqo + kk * 128 + c4);
                float4 wk4 = *(const float4*)(Wko + kk * 128 + c4);
                float4 wv4 = *(const float4*)(Wvo + kk * 128 + c4);
                fma4(aqo, xs, wq4);
                fma4(ak0, x0, wk4); fma4(ak1, x1, wk4);
                fma4(av0, x0, wv4); fma4(av1, x1, wv4);
            }
            #pragma unroll
            for (int kk = 0; kk < NACT; ++kk) {
                float4 wv4 = *(const float4*)(Wvo + (DD + kk) * 128 + c4);
                fma4(av0, sm[B_AO + r * NACT + kk], wv4);
                fma4(av1, sm[B_AO + (r + 16) * NACT + kk], wv4);
            }
            av0 = tanh4(av0); av1 = tanh4(av1);
            *(float4*)&sm[B_QO  + r * 132 + c4] = aqo;
            *(float4*)&sm[B_AVO + r * 132 + c4] = av0;
            *(float4*)&sm[B_AVO + (r + 16) * 132 + c4] = av1;
            sm[B_KOT + (c4 + 0) * 33 + r] = ak0.x; sm[B_KOT + (c4 + 1) * 33 + r] = ak0.y;
            sm[B_KOT + (c4 + 2) * 33 + r] = ak0.z; sm[B_KOT + (c4 + 3) * 33 + r] = ak0.w;
            sm[B_KOT + (c4 + 0) * 33 + r + 16] = ak1.x; sm[B_KOT + (c4 + 1) * 33 + r + 16] = ak1.y;
            sm[B_KOT + (c4 + 2) * 33 + r + 16] = ak1.z; sm[B_KOT + (c4 + 3) * 33 + r + 16] = ak1.w;
        }
        __syncthreads();
        // ---------- P2: scores_o[i][m] ----------
        {
            int i = t >> 5, m = t & 31;
            float acc = 0.f;
            #pragma unroll 8
            for (int d = 0; d < DD; ++d) acc += sm[B_QO + i * 132 + d] * sm[B_KOT + d * 33 + m];
            sm[B_WO + i * 33 + m] = acc * scale;
        }
        __syncthreads();
        // ---------- P3: softmax over agent axis i (per column m) ----------
        if (t < MM) {
            float mx = -1e30f;
            #pragma unroll
            for (int i = 0; i < NN; ++i) mx = fmaxf(mx, sm[B_WO + i * 33 + t]);
            float e[NN], sum = 0.f;
            #pragma unroll
            for (int i = 0; i < NN; ++i) { e[i] = expf(sm[B_WO + i * 33 + t] - mx); sum += e[i]; }
            float inv = 1.f / sum;
            #pragma unroll
            for (int i = 0; i < NN; ++i) sm[B_WO + i * 33 + t] = e[i] * inv;
        }
        __syncthreads();
        // ---------- P4: Po = avo @ W1b ----------
        {
            int r = t >> 4, h4 = (t & 15) * 4;
            float4 acc = {0,0,0,0};
            #pragma unroll 4
            for (int kk = 0; kk < DD; ++kk) {
                float4 w4 = *(const float4*)(W1 + (DD + kk) * HH + h4);
                fma4(acc, sm[B_AVO + r * 132 + kk], w4);
            }
            *(float4*)&sm[B_PO + r * 68 + h4] = acc;
        }
        __syncthreads();
        // ---------- P5: write weight_o; Uo = wo @ Po ----------
        out[2 * NB * 256 + b * 512 + t] = sm[B_WO + (t >> 5) * 33 + (t & 31)];
        {
            int i = t >> 5, h2 = (t & 31) * 2;
            float u0 = 0.f, u1 = 0.f;
            #pragma unroll
            for (int m = 0; m < MM; ++m) {
                float wv = sm[B_WO + i * 33 + m];
                u0 += wv * sm[B_PO + m * 68 + h2];
                u1 += wv * sm[B_PO + m * 68 + h2 + 1];
            }
            *(float2*)(g_ws + WS_UO + b * 1024 + i * 64 + h2) = make_float2(u0, u1);
        }
    }
}

// grid 128: value epilogue. value[i,j] = sum_h lrelu(U[i,h] + w[i,j] V[j,h]) W2[h]
__launch_bounds__(256, 4)
__global__ void k_fin(const float* __restrict__ W2, float* __restrict__ out) {
    __shared__ float s_U[16 * 68];
    __shared__ float s_V[16 * 68];
    __shared__ float s_w[16 * 17];
    __shared__ float s_W2[HH];
    const int b = blockIdx.x, t = threadIdx.x;

    s_w[(t >> 4) * 17 + (t & 15)] = g_ws[WS_W + b * 256 + t];
    #pragma unroll
    for (int u = 0; u < 4; ++u) {
        int idx = t + u * 256;
        int i = idx >> 6, h = idx & 63;
        s_U[i * 68 + h] = g_ws[WS_US + b * 1024 + idx] + g_ws[WS_UO + b * 1024 + idx];
        s_V[i * 68 + h] = g_ws[WS_V + b * 1024 + idx];
    }
    if (t < HH) s_W2[t] = W2[t];
    __syncthreads();

    int i = t >> 4, j = t & 15;
    float wij = s_w[i * 17 + j];
    float acc = 0.f;
    #pragma unroll
    for (int h = 0; h < HH; ++h) {
        float x = s_U[i * 68 + h] + wij * s_V[j * 68 + h];
        x = (x > 0.f) ? x : 0.01f * x;
        acc += x * s_W2[h];
    }
    out[b * 256 + t] = acc;
}

extern "C" void kernel_launch(void* const* d_in, const int* in_sizes, int n_in,
                              void* d_out, int out_size, void* d_ws, size_t ws_size,
                              hipStream_t stream) {
    const float* states    = (const float*)d_in[0];
    const float* policies  = (const float*)d_in[1];
    const float* actions   = (const float*)d_in[2];
    const float* states_o  = (const float*)d_in[3];
    const float* actions_o = (const float*)d_in[4];
    const float* Wk        = (const float*)d_in[5];
    const float* Wq        = (const float*)d_in[6];
    const float* Wv        = (const float*)d_in[7];
    const float* Wk_o      = (const float*)d_in[8];
    const float* Wq_o      = (const float*)d_in[9];
    const float* Wv_o      = (const float*)d_in[10];
    const float* W1        = (const float*)d_in[11];
    const float* W2        = (const float*)d_in[12];
    float* out = (float*)d_out;

    hipLaunchKernelGGL(k_sides, dim3(256), dim3(512), 0, stream,
                       states, policies, actions, states_o, actions_o,
                       Wq, Wk, Wv, Wq_o, Wk_o, Wv_o, W1, out);
    hipLaunchKernelGGL(k_fin, dim3(128), dim3(256), 0, stream, W2, out);
}

// Round 10
// 102.175 us; speedup vs baseline: 1.2180x; 1.1569x over previous
//
#include <hip/hip_runtime.h>
#include <math.h>

#define NB 128
#define NN 16
#define MM 32
#define DD 128
#define NACT 8
#define HH 64

// ---- static device scratch; every element rewritten by k_main each call ----
#define WS_W  0                     // weight  [128][256]
#define WS_WO 32768                 // weight_o[128][512]
#define WS_P  98304                 // P  = avact@W1a [128][16][64]
#define WS_V  229376                // V  = diff @W1a [128][16][64]
#define WS_PO 360448                // Po = avo  @W1b [128][32][64]
#define WS_FLOATS 622592            // ~2.5 MB

__device__ float g_ws[WS_FLOATS];

__device__ __forceinline__ float4 tanh4(float4 v) {
    float4 r; r.x = tanhf(v.x); r.y = tanhf(v.y); r.z = tanhf(v.z); r.w = tanhf(v.w); return r;
}
__device__ __forceinline__ void fma4(float4& a, float s, const float4& w) {
    a.x += s * w.x; a.y += s * w.y; a.z += s * w.z; a.w += s * w.w;
}

// grid 512 = 4 units x 128 batches. unit = blockIdx>>7 so co-resident blocks
// (bid, bid+256) are DIFFERENT units -> phase diversity on each CU.
__launch_bounds__(256, 2)
__global__ void k_main(const float* __restrict__ states,   const float* __restrict__ policies,
                       const float* __restrict__ actions,  const float* __restrict__ states_o,
                       const float* __restrict__ actions_o,
                       const float* __restrict__ Wq,  const float* __restrict__ Wk,
                       const float* __restrict__ Wv,  const float* __restrict__ Wqo,
                       const float* __restrict__ Wko, const float* __restrict__ Wvo,
                       const float* __restrict__ W1,  float* __restrict__ out) {
    __shared__ float sm[13200];
    const int unit = blockIdx.x >> 7;
    const int b = blockIdx.x & 127;
    const int t = threadIdx.x;
    const float scale = 0.08838834764831845f;   // 1/sqrt(128)

    if (unit == 0) {
        // ---------------- A1: q,k -> score -> softmax -> w ----------------
        float* s_st = sm;            // [16][132]
        float* s_q  = sm + 2112;     // [16][132]
        float* s_k  = sm + 4224;     // [16][132]
        float* s_w  = sm + 6336;     // [16][17]
        {
            int row = t >> 5, c4 = (t & 31) * 4;
            *(float4*)&s_st[row * 132 + c4] = *(const float4*)(states + b * 2048 + row * 128 + c4);
            int t2 = t + 256, row2 = t2 >> 5, c42 = (t2 & 31) * 4;
            *(float4*)&s_st[row2 * 132 + c42] = *(const float4*)(states + b * 2048 + row2 * 128 + c42);
        }
        __syncthreads();
        {
            const int p = t >> 5, c4 = (t & 31) * 4;
            float4 q0 = {0,0,0,0}, q1 = {0,0,0,0}, k0 = {0,0,0,0}, k1 = {0,0,0,0};
            #pragma unroll 4
            for (int kk = 0; kk < DD; ++kk) {
                float x0 = s_st[(2 * p) * 132 + kk], x1 = s_st[(2 * p + 1) * 132 + kk];
                float4 wq = *(const float4*)(Wq + kk * 128 + c4);
                float4 wk = *(const float4*)(Wk + kk * 128 + c4);
                fma4(q0, x0, wq); fma4(q1, x1, wq);
                fma4(k0, x0, wk); fma4(k1, x1, wk);
            }
            *(float4*)&s_q[(2 * p) * 132 + c4] = q0; *(float4*)&s_q[(2 * p + 1) * 132 + c4] = q1;
            *(float4*)&s_k[(2 * p) * 132 + c4] = k0; *(float4*)&s_k[(2 * p + 1) * 132 + c4] = k1;
        }
        __syncthreads();
        {
            int i = t >> 4, j = t & 15;
            float acc = 0.f;
            #pragma unroll 8
            for (int d = 0; d < DD; ++d) acc += s_q[i * 132 + d] * s_k[j * 132 + d];
            s_w[i * 17 + j] = acc * scale;
        }
        __syncthreads();
        if (t < NN) {
            float mx = -1e30f;
            #pragma unroll
            for (int j = 0; j < NN; ++j) mx = fmaxf(mx, s_w[t * 17 + j]);
            float e[NN], sum = 0.f;
            #pragma unroll
            for (int j = 0; j < NN; ++j) { e[j] = expf(s_w[t * 17 + j] - mx); sum += e[j]; }
            float inv = 1.f / sum;
            #pragma unroll
            for (int j = 0; j < NN; ++j) s_w[t * 17 + j] = e[j] * inv;
        }
        __syncthreads();
        {
            float wv = s_w[(t >> 4) * 17 + (t & 15)];
            out[NB * 256 + b * 256 + t] = wv;
            g_ws[WS_W + b * 256 + t] = wv;
        }
    } else if (unit == 1) {
        // ---------------- A2: avact/diff -> P = avact@W1a, V = diff@W1a ----------------
        float* s_st = sm;            // [16][132]
        float* s_aa = sm + 2112;     // [16][132]
        float* s_df = sm + 4224;     // [16][132]
        float* s_ac = sm + 6336;     // [16][8]
        float* s_po = sm + 6464;     // [16][8]
        {
            int row = t >> 5, c4 = (t & 31) * 4;
            *(float4*)&s_st[row * 132 + c4] = *(const float4*)(states + b * 2048 + row * 128 + c4);
            int t2 = t + 256, row2 = t2 >> 5, c42 = (t2 & 31) * 4;
            *(float4*)&s_st[row2 * 132 + c42] = *(const float4*)(states + b * 2048 + row2 * 128 + c42);
            if (t < 128) {
                s_ac[t] = actions [b * 128 + t];
                s_po[t] = policies[b * 128 + t];
            }
        }
        __syncthreads();
        {
            const int p = t >> 5, c4 = (t & 31) * 4;
            float4 a0 = {0,0,0,0}, a1 = {0,0,0,0};
            #pragma unroll 8
            for (int kk = 0; kk < DD; ++kk) {
                float4 wv = *(const float4*)(Wv + kk * 128 + c4);
                fma4(a0, s_st[(2 * p) * 132 + kk], wv);
                fma4(a1, s_st[(2 * p + 1) * 132 + kk], wv);
            }
            float4 aa0 = a0, aa1 = a1, ap0 = a0, ap1 = a1;
            #pragma unroll
            for (int k = 0; k < NACT; ++k) {
                float4 wv = *(const float4*)(Wv + (DD + k) * 128 + c4);
                fma4(aa0, s_ac[(2 * p) * 8 + k], wv); fma4(aa1, s_ac[(2 * p + 1) * 8 + k], wv);
                fma4(ap0, s_po[(2 * p) * 8 + k], wv); fma4(ap1, s_po[(2 * p + 1) * 8 + k], wv);
            }
            aa0 = tanh4(aa0); aa1 = tanh4(aa1); ap0 = tanh4(ap0); ap1 = tanh4(ap1);
            float4 d0, d1;
            d0.x = ap0.x - aa0.x; d0.y = ap0.y - aa0.y; d0.z = ap0.z - aa0.z; d0.w = ap0.w - aa0.w;
            d1.x = ap1.x - aa1.x; d1.y = ap1.y - aa1.y; d1.z = ap1.z - aa1.z; d1.w = ap1.w - aa1.w;
            *(float4*)&s_aa[(2 * p) * 132 + c4] = aa0; *(float4*)&s_aa[(2 * p + 1) * 132 + c4] = aa1;
            *(float4*)&s_df[(2 * p) * 132 + c4] = d0;  *(float4*)&s_df[(2 * p + 1) * 132 + c4] = d1;
        }
        __syncthreads();
        {
            const int i = t >> 4, h4 = (t & 15) * 4;
            float4 pa = {0,0,0,0}, va = {0,0,0,0};
            #pragma unroll 8
            for (int kk = 0; kk < DD; ++kk) {
                float4 w4 = *(const float4*)(W1 + kk * HH + h4);
                fma4(pa, s_aa[i * 132 + kk], w4);
                fma4(va, s_df[i * 132 + kk], w4);
            }
            *(float4*)(g_ws + WS_P + b * 1024 + i * 64 + h4) = pa;
            *(float4*)(g_ws + WS_V + b * 1024 + i * 64 + h4) = va;
        }
    } else if (unit == 2) {
        // ---------------- B1: qo,ko -> score_o -> softmax_o -> wo ----------------
        float* s_st  = sm;           // [16][132]
        float* s_qo  = sm + 2112;    // [16][132]
        float* s_sto = sm + 4224;    // [32][132]
        float* s_koT = sm + 8448;    // [128][33]
        float* s_wo  = sm + 12672;   // [16][33]
        {
            int row = t >> 5, c4 = (t & 31) * 4;
            *(float4*)&s_st[row * 132 + c4] = *(const float4*)(states + b * 2048 + row * 128 + c4);
            int t2 = t + 256, row2 = t2 >> 5, c42 = (t2 & 31) * 4;
            *(float4*)&s_st[row2 * 132 + c42] = *(const float4*)(states + b * 2048 + row2 * 128 + c42);
            #pragma unroll
            for (int u = 0; u < 4; ++u) {
                int f = t + u * 256, r = f >> 5, cc = (f & 31) * 4;
                *(float4*)&s_sto[r * 132 + cc] = *(const float4*)(states_o + b * 4096 + r * 128 + cc);
            }
        }
        __syncthreads();
        {
            const int p = t >> 5, c4 = (t & 31) * 4;
            float4 g0 = {0,0,0,0}, g1 = {0,0,0,0};
            float4 o0 = {0,0,0,0}, o1 = {0,0,0,0}, o2 = {0,0,0,0}, o3 = {0,0,0,0};
            #pragma unroll 4
            for (int kk = 0; kk < DD; ++kk) {
                float4 wq = *(const float4*)(Wqo + kk * 128 + c4);
                float4 wk = *(const float4*)(Wko + kk * 128 + c4);
                fma4(g0, s_st[(2 * p) * 132 + kk], wq);
                fma4(g1, s_st[(2 * p + 1) * 132 + kk], wq);
                fma4(o0, s_sto[(4 * p) * 132 + kk], wk);
                fma4(o1, s_sto[(4 * p + 1) * 132 + kk], wk);
                fma4(o2, s_sto[(4 * p + 2) * 132 + kk], wk);
                fma4(o3, s_sto[(4 * p + 3) * 132 + kk], wk);
            }
            *(float4*)&s_qo[(2 * p) * 132 + c4] = g0;
            *(float4*)&s_qo[(2 * p + 1) * 132 + c4] = g1;
            s_koT[(c4+0)*33 + 4*p]   = o0.x; s_koT[(c4+1)*33 + 4*p]   = o0.y; s_koT[(c4+2)*33 + 4*p]   = o0.z; s_koT[(c4+3)*33 + 4*p]   = o0.w;
            s_koT[(c4+0)*33 + 4*p+1] = o1.x; s_koT[(c4+1)*33 + 4*p+1] = o1.y; s_koT[(c4+2)*33 + 4*p+1] = o1.z; s_koT[(c4+3)*33 + 4*p+1] = o1.w;
            s_koT[(c4+0)*33 + 4*p+2] = o2.x; s_koT[(c4+1)*33 + 4*p+2] = o2.y; s_koT[(c4+2)*33 + 4*p+2] = o2.z; s_koT[(c4+3)*33 + 4*p+2] = o2.w;
            s_koT[(c4+0)*33 + 4*p+3] = o3.x; s_koT[(c4+1)*33 + 4*p+3] = o3.y; s_koT[(c4+2)*33 + 4*p+3] = o3.z; s_koT[(c4+3)*33 + 4*p+3] = o3.w;
        }
        __syncthreads();
        {
            int i = t >> 5, m = t & 31;
            float a0 = 0.f, a1 = 0.f;
            #pragma unroll 8
            for (int d = 0; d < DD; ++d) {
                float kv = s_koT[d * 33 + m];
                a0 += s_qo[i * 132 + d] * kv;
                a1 += s_qo[(i + 8) * 132 + d] * kv;
            }
            s_wo[i * 33 + m] = a0 * scale;
            s_wo[(i + 8) * 33 + m] = a1 * scale;
        }
        __syncthreads();
        if (t < MM) {
            float mx = -1e30f;
            #pragma unroll
            for (int i = 0; i < NN; ++i) mx = fmaxf(mx, s_wo[i * 33 + t]);
            float e[NN], sum = 0.f;
            #pragma unroll
            for (int i = 0; i < NN; ++i) { e[i] = expf(s_wo[i * 33 + t] - mx); sum += e[i]; }
            float inv = 1.f / sum;
            #pragma unroll
            for (int i = 0; i < NN; ++i) s_wo[i * 33 + t] = e[i] * inv;
        }
        __syncthreads();
        {
            float w0 = s_wo[(t >> 5) * 33 + (t & 31)];
            float w1 = s_wo[((t + 256) >> 5) * 33 + (t & 31)];
            out[2 * NB * 256 + b * 512 + t] = w0;
            out[2 * NB * 256 + b * 512 + 256 + t] = w1;
            g_ws[WS_WO + b * 512 + t] = w0;
            g_ws[WS_WO + b * 512 + 256 + t] = w1;
        }
    } else {
        // ---------------- B2: avo -> Po = avo@W1b ----------------
        float* s_sto = sm;           // [32][132]
        float* s_avo = sm + 4224;    // [32][132]
        float* s_ao  = sm + 8448;    // [32][8]
        {
            #pragma unroll
            for (int u = 0; u < 4; ++u) {
                int f = t + u * 256, r = f >> 5, cc = (f & 31) * 4;
                *(float4*)&s_sto[r * 132 + cc] = *(const float4*)(states_o + b * 4096 + r * 128 + cc);
            }
            s_ao[t] = actions_o[b * 256 + t];
        }
        __syncthreads();
        {
            const int p = t >> 5, c4 = (t & 31) * 4;
            float4 v0 = {0,0,0,0}, v1 = {0,0,0,0}, v2 = {0,0,0,0}, v3 = {0,0,0,0};
            #pragma unroll 8
            for (int kk = 0; kk < DD; ++kk) {
                float4 wv = *(const float4*)(Wvo + kk * 128 + c4);
                fma4(v0, s_sto[(4 * p) * 132 + kk], wv);
                fma4(v1, s_sto[(4 * p + 1) * 132 + kk], wv);
                fma4(v2, s_sto[(4 * p + 2) * 132 + kk], wv);
                fma4(v3, s_sto[(4 * p + 3) * 132 + kk], wv);
            }
            #pragma unroll
            for (int k = 0; k < NACT; ++k) {
                float4 wv = *(const float4*)(Wvo + (DD + k) * 128 + c4);
                fma4(v0, s_ao[(4 * p) * 8 + k], wv);
                fma4(v1, s_ao[(4 * p + 1) * 8 + k], wv);
                fma4(v2, s_ao[(4 * p + 2) * 8 + k], wv);
                fma4(v3, s_ao[(4 * p + 3) * 8 + k], wv);
            }
            *(float4*)&s_avo[(4 * p) * 132 + c4]     = tanh4(v0);
            *(float4*)&s_avo[(4 * p + 1) * 132 + c4] = tanh4(v1);
            *(float4*)&s_avo[(4 * p + 2) * 132 + c4] = tanh4(v2);
            *(float4*)&s_avo[(4 * p + 3) * 132 + c4] = tanh4(v3);
        }
        __syncthreads();
        {
            const int r = t >> 4, h4 = (t & 15) * 4;
            float4 p0 = {0,0,0,0}, p1 = {0,0,0,0};
            #pragma unroll 8
            for (int kk = 0; kk < DD; ++kk) {
                float4 w4 = *(const float4*)(W1 + (DD + kk) * HH + h4);
                fma4(p0, s_avo[r * 132 + kk], w4);
                fma4(p1, s_avo[(r + 16) * 132 + kk], w4);
            }
            *(float4*)(g_ws + WS_PO + b * 2048 + r * 64 + h4) = p0;
            *(float4*)(g_ws + WS_PO + b * 2048 + (r + 16) * 64 + h4) = p1;
        }
    }
}

// grid 128: U = w@P + wo@Po; value[i,j] = sum_h lrelu(U[i,h] + w[i,j] V[j,h]) W2[h]
__launch_bounds__(256, 2)
__global__ void k_fin(const float* __restrict__ W2, float* __restrict__ out) {
    __shared__ float s_w [16 * 17];
    __shared__ float s_wo[16 * 33];
    __shared__ float s_P [16 * 64];
    __shared__ float s_Po[32 * 64];
    __shared__ float s_V [16 * 68];
    __shared__ float s_U [16 * 68];
    __shared__ float s_W2[HH];
    const int b = blockIdx.x, t = threadIdx.x;

    s_w[(t >> 4) * 17 + (t & 15)] = g_ws[WS_W + b * 256 + t];
    s_wo[(t >> 5) * 33 + (t & 31)] = g_ws[WS_WO + b * 512 + t];
    s_wo[((t + 256) >> 5) * 33 + (t & 31)] = g_ws[WS_WO + b * 512 + 256 + t];
    ((float4*)s_P)[t] = ((const float4*)(g_ws + WS_P + b * 1024))[t];
    ((float4*)s_Po)[t] = ((const float4*)(g_ws + WS_PO + b * 2048))[t];
    ((float4*)s_Po)[t + 256] = ((const float4*)(g_ws + WS_PO + b * 2048))[t + 256];
    #pragma unroll
    for (int u = 0; u < 4; ++u) {
        int idx = t + u * 256;
        s_V[(idx >> 6) * 68 + (idx & 63)] = g_ws[WS_V + b * 1024 + idx];
    }
    if (t < HH) s_W2[t] = W2[t];
    __syncthreads();

    {
        int i = t >> 4, h4 = (t & 15) * 4;
        float4 u = {0,0,0,0};
        #pragma unroll
        for (int k = 0; k < NN; ++k) fma4(u, s_w[i * 17 + k], *(const float4*)&s_P[k * 64 + h4]);
        #pragma unroll
        for (int m = 0; m < MM; ++m) fma4(u, s_wo[i * 33 + m], *(const float4*)&s_Po[m * 64 + h4]);
        *(float4*)&s_U[i * 68 + h4] = u;
    }
    __syncthreads();

    {
        int i = t >> 4, j = t & 15;
        float wij = s_w[i * 17 + j];
        float acc = 0.f;
        #pragma unroll
        for (int h = 0; h < HH; ++h) {
            float x = s_U[i * 68 + h] + wij * s_V[j * 68 + h];
            x = (x > 0.f) ? x : 0.01f * x;
            acc += x * s_W2[h];
        }
        out[b * 256 + t] = acc;
    }
}

extern "C" void kernel_launch(void* const* d_in, const int* in_sizes, int n_in,
                              void* d_out, int out_size, void* d_ws, size_t ws_size,
                              hipStream_t stream) {
    const float* states    = (const float*)d_in[0];
    const float* policies  = (const float*)d_in[1];
    const float* actions   = (const float*)d_in[2];
    const float* states_o  = (const float*)d_in[3];
    const float* actions_o = (const float*)d_in[4];
    const float* Wk        = (const float*)d_in[5];
    const float* Wq        = (const float*)d_in[6];
    const float* Wv        = (const float*)d_in[7];
    const float* Wk_o      = (const float*)d_in[8];
    const float* Wq_o      = (const float*)d_in[9];
    const float* Wv_o      = (const float*)d_in[10];
    const float* W1        = (const float*)d_in[11];
    const float* W2        = (const float*)d_in[12];
    float* out = (float*)d_out;

    hipLaunchKernelGGL(k_main, dim3(512), dim3(256), 0, stream,
                       states, policies, actions, states_o, actions_o,
                       Wq, Wk, Wv, Wq_o, Wk_o, Wv_o, W1, out);
    hipLaunchKernelGGL(k_fin, dim3(128), dim3(256), 0, stream, W2, out);
}